// Round 1
// baseline (202.504 us; speedup 1.0000x reference)
//
#include <hip/hip_runtime.h>
#include <math.h>

namespace {
constexpr int kUnits = 128;
constexpr int kSteps = 2048;
constexpr int kBatch = 32;
constexpr int kPF = 16;                       // prefetch depth (steps)
constexpr int kChainElems = kSteps * kUnits;  // elements per batch-chain block
constexpr int kBlkOff = kPF * kUnits;
constexpr int kNBlk = kSteps / kPF;
}

// One thread per (b,u) chain: 4096 threads = 64 waves, one per SIMD on 64 CUs.
// Phase tracked as (cos,sin) pair advanced by composed rotations -> no sincos
// in the hot loop. 16-step register prefetch queue hides L2/L3 load latency.
__global__ __launch_bounds__(64, 1)
void hopf_scan_kernel(const float* __restrict__ Xr,
                      const float* __restrict__ Xi,
                      const float* __restrict__ Om,
                      float* __restrict__ Zr,
                      float* __restrict__ Zi) {
  const float DTf = (float)(1.0 / 173.61);
  const float nscale = -(0.1f * DTf);   // eps = nscale * xi * s

  const int gid = blockIdx.x * 64 + threadIdx.x;  // 0..4095
  const int u = gid & (kUnits - 1);
  const int b = gid >> 7;

  // Per-step constant rotation by omega*dt, computed accurately once.
  const float omega = Om[u];
  const double wd = (double)omega * (double)DTf;
  double sd, cd;
  sincos(wd, &sd, &cd);
  const float cw = (float)cd;
  const float sw = (float)sd;
  // residual phase lost in the f64->f32 cast of (cw,sw); folded into eps
  const float elo = (float)(wd - atan2((double)sw, (double)cw));

  // state: r, (c,s) = (cos phi, sin phi); phi0 = 0, r0 = 1
  float c = 1.0f, s = 0.0f, r = 1.0f;

  const long long base = (long long)b * kChainElems + u;
  const float* pxr = Xr + base;
  const float* pxi = Xi + base;
  float* pzr = Zr + base;
  float* pzi = Zi + base;

  // warm the prefetch queue
  float bR[kPF], bI[kPF];
#pragma unroll
  for (int j = 0; j < kPF; ++j) {
    bR[j] = pxr[j * kUnits];
    bI[j] = pxi[j * kUnits];
  }

  for (int blk = 0; blk < kNBlk; ++blk) {
    // renormalize (c,s): drift is ~2e-7/step, 1st-order Newton is exact enough
    float n2 = fmaf(c, c, s * s);
    float inv = fmaf(-0.5f, n2, 1.5f);
    c *= inv;
    s *= inv;

    // prefetch source: next block; on the last block wrap to a valid (dummy) addr
    const int poff = (blk + 1 < kNBlk) ? kBlkOff : (kBlkOff - kChainElems);
    const float* qr = pxr + poff;
    const float* qi = pxi + poff;

#pragma unroll
    for (int j = 0; j < kPF; ++j) {
      const float xr = bR[j];
      const float xi = bI[j];
      bR[j] = qr[j * kUnits];
      bI[j] = qi[j * kUnits];

      // phase advance: rotate (c,s) by (omega*dt + eps), eps = -0.1*dt*xi*s
      const float ax = xi * nscale;
      const float eps = fmaf(ax, s, elo);
      const float A = fmaf(-sw, eps, cw);   // cos(wdt + eps) to 1st order
      const float B = fmaf(cw, eps, sw);    // sin(wdt + eps) to 1st order
      const float bs = B * s;
      const float c2 = fmaf(A, c, -bs);
      const float bc = B * c;
      const float s2 = fmaf(A, s, bc);

      // r update uses OLD c (= cos phi_{t-1}), matching the reference order
      const float rr = r * r;
      const float om1 = fmaf(-0.01f, rr, 1.0f);   // 1 - beta*r^2
      const float t1 = om1 * r;
      const float inr = (0.1f * xr) * c;
      const float sum = t1 + inr;
      r = fmaf(sum, DTf, r);

      c = c2;
      s = s2;

      // outputs use post-update r, phi
      __builtin_nontemporal_store(r * c, &pzr[j * kUnits]);
      __builtin_nontemporal_store(r * s, &pzi[j * kUnits]);
    }
    pxr += kBlkOff;
    pxi += kBlkOff;
    pzr += kBlkOff;
    pzi += kBlkOff;
  }
}

extern "C" void kernel_launch(void* const* d_in, const int* in_sizes, int n_in,
                              void* d_out, int out_size, void* d_ws, size_t ws_size,
                              hipStream_t stream) {
  const float* Xr = (const float*)d_in[0];
  const float* Xi = (const float*)d_in[1];
  const float* Om = (const float*)d_in[2];
  float* Zr = (float*)d_out;                                // z_real [B,T,U]
  float* Zi = (float*)d_out + (long long)kBatch * kChainElems;  // z_imag [B,T,U]

  dim3 grid(kBatch * kUnits / 64);  // 64 blocks
  dim3 block(64);
  hipLaunchKernelGGL(hopf_scan_kernel, grid, block, 0, stream, Xr, Xi, Om, Zr, Zi);
}